// Round 4
// baseline (8094.862 us; speedup 1.0000x reference)
//
#include <hip/hip_runtime.h>
#include <cmath>

#define DD   512
#define HH   1024
#define BB   4
#define SS   4096
#define CHK  64
#define NCHK 64
#define TOK  256
#define SA   72   /* padded LDS row stride in bf16 elements */
#define GRID_BLKS 256

static constexpr float ERRSCALE = 2.0f / (float)(TOK * DD);

typedef __attribute__((ext_vector_type(8))) short bf16x8;
typedef __attribute__((ext_vector_type(4))) float f32x4;

__device__ __forceinline__ float sigmoidf_(float v) { return 1.0f / (1.0f + expf(-v)); }
__device__ __forceinline__ float clip1f_(float v) { return fminf(fmaxf(v, -1.0f), 1.0f); }

__device__ __forceinline__ ushort f2b(float f) {
    union { float f; unsigned u; } v; v.f = f;
    return (ushort)((v.u + 0x7fffu + ((v.u >> 16) & 1u)) >> 16);
}
__device__ __forceinline__ float b2f(ushort u) {
    union { unsigned u; float f; } v; v.u = ((unsigned)u) << 16;
    return v.f;
}

// ---------------------------------------------------------------------------
// Device-scope sense-reversing grid barrier (plain launch, no cooperative API).
// cnt/gen zeroed host-side before the scan launch each call.
// ---------------------------------------------------------------------------
__device__ __forceinline__ void gbar(unsigned* cnt, unsigned* gen) {
    __syncthreads();
    if (threadIdx.x == 0) {
        __threadfence();   // agent-scope release: publish all prior writes
        const unsigned g = __hip_atomic_load(gen, __ATOMIC_RELAXED, __HIP_MEMORY_SCOPE_AGENT);
        const unsigned a = __hip_atomic_fetch_add(cnt, 1u, __ATOMIC_ACQ_REL, __HIP_MEMORY_SCOPE_AGENT);
        if (a == GRID_BLKS - 1) {
            __hip_atomic_store(cnt, 0u, __ATOMIC_RELAXED, __HIP_MEMORY_SCOPE_AGENT);
            __hip_atomic_fetch_add(gen, 1u, __ATOMIC_RELEASE, __HIP_MEMORY_SCOPE_AGENT);
        } else {
            while (__hip_atomic_load(gen, __ATOMIC_RELAXED, __HIP_MEMORY_SCOPE_AGENT) == g)
                __builtin_amdgcn_s_sleep(2);
        }
        __threadfence();   // agent-scope acquire: see other blocks' writes
    }
    __syncthreads();
}

// ---------------------------------------------------------------------------
// LDS staging (canonical layout S[row][k], row stride SA)
// ---------------------------------------------------------------------------
__device__ __forceinline__ void stage_n(const ushort* __restrict__ G, int ld,
                                        int r0, int k0, ushort* S, int tid) {
#pragma unroll
    for (int p = 0; p < 2; ++p) {
        const int c = tid + p * 256;
        const int r = c >> 3, o = c & 7;
        *(float4*)(S + r * SA + o * 8) =
            *(const float4*)(G + (size_t)(r0 + r) * ld + k0 + o * 8);
    }
}
__device__ __forceinline__ void stage_t(const ushort* __restrict__ G, int ld,
                                        int c0, int k0, ushort* S, int tid) {
    const int kr = tid & 63;
    const int mo0 = (tid >> 6) * 2;
#pragma unroll
    for (int p = 0; p < 2; ++p) {
        const int mo = (mo0 + p) * 8;
        const float4 v = *(const float4*)(G + (size_t)(k0 + kr) * ld + c0 + mo);
        ushort u[8];
        __builtin_memcpy(u, &v, 16);
#pragma unroll
        for (int j = 0; j < 8; ++j) S[(mo + j) * SA + kr] = u[j];
    }
}

// 64x64 block tile MFMA core, 4 waves of 32x32, K steps of 64.
__device__ __forceinline__ void gemm_core(
    const ushort* __restrict__ A, int lda, bool ta,
    const ushort* __restrict__ B, int ldb, bool tb,
    int K, int m0, int n0, ushort* As, ushort* Bs, f32x4 acc[2][2])
{
    const int tid = threadIdx.x;
    const int lane = tid & 63;
    const int w = tid >> 6;
    const int wr = (w >> 1) * 32, wc = (w & 1) * 32;
    const int lr = lane & 15, lg = lane >> 4;

    for (int k0 = 0; k0 < K; k0 += 64) {
        if (ta) stage_t(A, lda, m0, k0, As, tid); else stage_n(A, lda, m0, k0, As, tid);
        if (tb) stage_t(B, ldb, n0, k0, Bs, tid); else stage_n(B, ldb, n0, k0, Bs, tid);
        __syncthreads();
#pragma unroll
        for (int ks = 0; ks < 2; ++ks) {
            bf16x8 af[2], bfr[2];
#pragma unroll
            for (int mi = 0; mi < 2; ++mi)
                af[mi] = *(const bf16x8*)(As + (wr + mi * 16 + lr) * SA + ks * 32 + lg * 8);
#pragma unroll
            for (int ni = 0; ni < 2; ++ni)
                bfr[ni] = *(const bf16x8*)(Bs + (wc + ni * 16 + lr) * SA + ks * 32 + lg * 8);
#pragma unroll
            for (int mi = 0; mi < 2; ++mi)
#pragma unroll
                for (int ni = 0; ni < 2; ++ni)
                    acc[mi][ni] = __builtin_amdgcn_mfma_f32_16x16x32_bf16(
                        af[mi], bfr[ni], acc[mi][ni], 0, 0, 0);
        }
        __syncthreads();
    }
}

template<typename F>
__device__ __forceinline__ void epilogue(int m0, int n0, const f32x4 acc[2][2], F&& f) {
    const int lane = threadIdx.x & 63, w = threadIdx.x >> 6;
    const int wr = (w >> 1) * 32, wc = (w & 1) * 32;
    const int lr = lane & 15, lg = lane >> 4;
#pragma unroll
    for (int mi = 0; mi < 2; ++mi)
#pragma unroll
        for (int ni = 0; ni < 2; ++ni)
#pragma unroll
            for (int r = 0; r < 4; ++r)
                f(m0 + wr + mi * 16 + lg * 4 + r, n0 + wc + ni * 16 + lr, acc[mi][ni][r]);
}

__device__ __forceinline__ void zacc(f32x4 acc[2][2]) {
#pragma unroll
    for (int i = 0; i < 2; ++i)
#pragma unroll
        for (int j = 0; j < 2; ++j) acc[i][j] = 0.0f;
}

// ---------------------------------------------------------------------------
// Scan phase ops
// ---------------------------------------------------------------------------
__device__ __forceinline__ void op_s1(const ushort* kt, const ushort* W1e,
                                      ushort* a1, float* ds, int tile,
                                      ushort* As, ushort* Bs) {
    f32x4 acc[2][2]; zacc(acc);
    const int m0 = (tile >> 4) * 64, n0 = (tile & 15) * 64;
    gemm_core(kt, DD, false, W1e, DD, false, DD, m0, n0, As, Bs, acc);
    epilogue(m0, n0, acc, [&](int r, int c, float v) {
        const size_t i = (size_t)r * HH + c;
        const float sg = sigmoidf_(v);
        a1[i] = f2b(v * sg);
        ds[i] = sg * (1.0f + v * (1.0f - sg));
    });
}

__device__ __forceinline__ void op_s2(const ushort* a1, const ushort* W2e,
                                      const ushort* vt, ushort* db2, int tile,
                                      ushort* As, ushort* Bs) {
    f32x4 acc[2][2]; zacc(acc);
    const int m0 = (tile >> 3) * 64, n0 = (tile & 7) * 64;
    gemm_core(a1, HH, false, W2e, HH, false, HH, m0, n0, As, Bs, acc);
    epilogue(m0, n0, acc, [&](int r, int c, float v) {
        const size_t i = (size_t)r * DD + c;
        const float e = clip1f_(v - b2f(vt[i]));
        db2[i] = f2b(e * ERRSCALE);
    });
}

__device__ __forceinline__ void op_s3(const ushort* db2, const ushort* W2e,
                                      const float* ds, ushort* db1, int tile,
                                      ushort* As, ushort* Bs) {
    f32x4 acc[2][2]; zacc(acc);
    const int m0 = (tile >> 4) * 64, n0 = (tile & 15) * 64;
    gemm_core(db2, DD, false, W2e, HH, true, DD, m0, n0, As, Bs, acc);
    epilogue(m0, n0, acc, [&](int r, int c, float v) {
        const size_t i = (size_t)r * HH + c;
        db1[i] = f2b(v * ds[i]);
    });
}

__device__ __forceinline__ void op_g1upd(const ushort* db1, const ushort* kt,
    float* m1, float* d1, const float* Wm1, ushort* W1n,
    float dec, float lrg, float eta, int tile, ushort* As, ushort* Bs) {
    f32x4 acc[2][2]; zacc(acc);
    const int i0 = (tile >> 3) * 64, j0 = (tile & 7) * 64;
    gemm_core(db1, HH, true, kt, DD, true, TOK, i0, j0, As, Bs, acc);
    epilogue(i0, j0, acc, [&](int r, int c, float v) {
        const size_t i = (size_t)r * DD + c;
        const float g = clip1f_(v);
        const float mn = eta * m1[i] - lrg * g;
        m1[i] = mn;
        const float dn = (1.0f - dec) * d1[i] + mn;
        d1[i] = dn;
        W1n[i] = f2b(Wm1[i] + dn);
    });
}

__device__ __forceinline__ void op_g2upd(const ushort* db2, const ushort* a1,
    float* m2, float* d2, const float* Wm2, ushort* W2n,
    float dec, float lrg, float eta, int tile, ushort* As, ushort* Bs) {
    f32x4 acc[2][2]; zacc(acc);
    const int i0 = (tile >> 4) * 64, j0 = (tile & 15) * 64;
    gemm_core(db2, DD, true, a1, HH, true, TOK, i0, j0, As, Bs, acc);
    epilogue(i0, j0, acc, [&](int r, int c, float v) {
        const size_t i = (size_t)r * HH + c;
        const float g = clip1f_(v);
        const float mn = eta * m2[i] - lrg * g;
        m2[i] = mn;
        const float dn = (1.0f - dec) * d2[i] + mn;
        d2[i] = dn;
        W2n[i] = f2b(Wm2[i] + dn);
    });
}

__device__ __forceinline__ void op_s6(const ushort* qt, const ushort* W1e,
                                      ushort* h, int tile, ushort* As, ushort* Bs) {
    f32x4 acc[2][2]; zacc(acc);
    const int m0 = (tile >> 4) * 64, n0 = (tile & 15) * 64;
    gemm_core(qt, DD, false, W1e, DD, false, DD, m0, n0, As, Bs, acc);
    epilogue(m0, n0, acc, [&](int r, int c, float v) {
        const float sg = sigmoidf_(v);
        h[(size_t)r * HH + c] = f2b(v * sg);
    });
}

__device__ __forceinline__ void op_s7(const ushort* h, const ushort* W2e,
                                      ushort* y, int tile, ushort* As, ushort* Bs) {
    f32x4 acc[2][2]; zacc(acc);
    const int m0 = (tile >> 3) * 64, n0 = (tile & 7) * 64;
    gemm_core(h, HH, false, W2e, HH, false, HH, m0, n0, As, Bs, acc);
    epilogue(m0, n0, acc, [&](int r, int c, float v) {
        y[(size_t)r * DD + c] = f2b(v);
    });
}

// ---------------------------------------------------------------------------
// Persistent scan kernel: all 64 chunks, 4 grid barriers per chunk.
// P1 = S3(t) || g2upd(t); P2 = g1upd(t); P3 = S6(t) || S1(t+1);
// P4 = S7(t) || S2(t+1).  Weights/activations parity double-buffered.
// ---------------------------------------------------------------------------
struct ScanArgs {
    const ushort *ktb, *vcb, *qtb;
    ushort *a1b0, *a1b1;
    float  *ds10, *ds11;
    ushort *db1b, *db2b0, *db2b1, *hbb;
    ushort *W1eb0, *W1eb1, *W2eb0, *W2eb1;
    float  *m1, *d1, *m2, *d2;
    const float *Wm1, *Wm2, *gates;
    ushort *ycall;
    unsigned *bcnt, *bgen;
};

__global__ __launch_bounds__(256) void scan_k(ScanArgs p) {
    __shared__ ushort As[64 * SA];
    __shared__ ushort Bs[64 * SA];
    const int bid = blockIdx.x;

    // prologue: chunk-0 forward
    if (bid < 64) op_s1(p.ktb, p.W1eb0, p.a1b0, p.ds10, bid, As, Bs);
    gbar(p.bcnt, p.bgen);
    if (bid < 32) op_s2(p.a1b0, p.W2eb0, p.vcb, p.db2b0, bid, As, Bs);
    gbar(p.bcnt, p.bgen);

    for (int t = 0; t < NCHK; ++t) {
        const int par = t & 1;
        const ushort* kt = p.ktb + (size_t)t * TOK * DD;
        const ushort* qt = p.qtb + (size_t)t * TOK * DD;
        ushort* a1c  = par ? p.a1b1 : p.a1b0;
        ushort* a1n  = par ? p.a1b0 : p.a1b1;
        float*  ds1c = par ? p.ds11 : p.ds10;
        float*  ds1n = par ? p.ds10 : p.ds11;
        ushort* db2c = par ? p.db2b1 : p.db2b0;
        ushort* db2n = par ? p.db2b0 : p.db2b1;
        ushort* W1n  = par ? p.W1eb0 : p.W1eb1;
        const ushort* W2o = par ? p.W2eb1 : p.W2eb0;
        ushort* W2n  = par ? p.W2eb0 : p.W2eb1;
        const float dec = p.gates[t];
        const float lrg = p.gates[NCHK + t];
        const float eta = p.gates[2 * NCHK + t];

        // P1: db1 = (db2 @ W2e_old) * silu'(pre1)  ||  g2 + m2/d2/W2e update
        if (bid < 64)
            op_s3(db2c, W2o, ds1c, p.db1b, bid, As, Bs);
        else if (bid < 192)
            op_g2upd(db2c, a1c, p.m2, p.d2, p.Wm2, W2n, dec, lrg, eta, bid - 64, As, Bs);
        gbar(p.bcnt, p.bgen);

        // P2: g1 + m1/d1/W1e update
        if (bid < 128)
            op_g1upd(p.db1b, kt, p.m1, p.d1, p.Wm1, W1n, dec, lrg, eta, bid, As, Bs);
        gbar(p.bcnt, p.bgen);

        // P3: h(t) = silu(q @ W1e_new^T)  ||  S1(t+1) with W1e_new
        if (bid < 64)
            op_s6(qt, W1n, p.hbb, bid, As, Bs);
        else if (bid < 128 && t + 1 < NCHK)
            op_s1(p.ktb + (size_t)(t + 1) * TOK * DD, W1n, a1n, ds1n, bid - 64, As, Bs);
        gbar(p.bcnt, p.bgen);

        // P4: y(t) = h @ W2e_new^T  ||  S2(t+1) with W2e_new
        if (bid < 32)
            op_s7(p.hbb, W2n, p.ycall + (size_t)t * TOK * DD, bid, As, Bs);
        else if (bid < 64 && t + 1 < NCHK)
            op_s2(a1n, W2n, p.vcb + (size_t)(t + 1) * TOK * DD, db2n, bid - 32, As, Bs);
        gbar(p.bcnt, p.bgen);
    }
}

// ---------------------------------------------------------------------------
// Pre/post kernels
// ---------------------------------------------------------------------------
__global__ __launch_bounds__(256) void conv_k(const float* __restrict__ s,
                                              ushort* __restrict__ d, int n4) {
    const int i = blockIdx.x * 256 + threadIdx.x;
    if (i < n4) {
        const float4 v = ((const float4*)s)[i];
        ushort4 o;
        o.x = f2b(v.x); o.y = f2b(v.y); o.z = f2b(v.z); o.w = f2b(v.w);
        ((ushort4*)d)[i] = o;
    }
}

template<int OM>
__global__ __launch_bounds__(256) void proj_k(const ushort* __restrict__ xb,
                                              const ushort* __restrict__ Wb,
                                              float* __restrict__ df,
                                              ushort* __restrict__ db) {
    __shared__ ushort As[64 * SA], Bs[64 * SA];
    f32x4 acc[2][2]; zacc(acc);
    const int m0 = blockIdx.y * 64, n0 = blockIdx.x * 64;
    gemm_core(xb, DD, false, Wb, DD, false, DD, m0, n0, As, Bs, acc);
    epilogue(m0, n0, acc, [&](int row, int col, float val) {
        const int b = row >> 12, s = row & (SS - 1);
        const int t = s >> 6, c = s & 63;
        const size_t orow = (size_t)((t << 8) | (b << 6) | c);
        if (OM == 0) df[orow * DD + col] = val;
        else         db[orow * DD + col] = f2b(val);
    });
}

__global__ __launch_bounds__(256) void l2n_k(const float* __restrict__ kp,
                                             const float* __restrict__ qp,
                                             ushort* __restrict__ kb,
                                             ushort* __restrict__ qb) {
    const float* src = blockIdx.y ? qp : kp;
    ushort* dst = blockIdx.y ? qb : kb;
    const int row = blockIdx.x * 4 + (threadIdx.x >> 6);
    const int lane = threadIdx.x & 63;
    const float4* p = (const float4*)(src + (size_t)row * DD);
    float4 v0 = p[lane], v1 = p[lane + 64];
    float ss = v0.x * v0.x + v0.y * v0.y + v0.z * v0.z + v0.w * v0.w
             + v1.x * v1.x + v1.y * v1.y + v1.z * v1.z + v1.w * v1.w;
#pragma unroll
    for (int m = 32; m >= 1; m >>= 1) ss += __shfl_xor(ss, m);
    const float sc = 1.0f / (sqrtf(ss) + 1e-8f);
    ushort4 o0, o1;
    o0.x = f2b(v0.x * sc); o0.y = f2b(v0.y * sc); o0.z = f2b(v0.z * sc); o0.w = f2b(v0.w * sc);
    o1.x = f2b(v1.x * sc); o1.y = f2b(v1.y * sc); o1.z = f2b(v1.z * sc); o1.w = f2b(v1.w * sc);
    *(ushort4*)(dst + (size_t)row * DD + lane * 4) = o0;
    *(ushort4*)(dst + (size_t)row * DD + 256 + lane * 4) = o1;
}

__global__ __launch_bounds__(256) void gates_tok_k(
    const float* __restrict__ x,
    const float* __restrict__ gdw, const float* __restrict__ gdb,
    const float* __restrict__ glw, const float* __restrict__ glb,
    const float* __restrict__ gmw, const float* __restrict__ gmb,
    float* __restrict__ gtok)
{
    const int wid = (blockIdx.x * 256 + threadIdx.x) >> 6;
    const int lane = threadIdx.x & 63;
    const int t = wid >> 8;
    const int rem = wid & 255;
    const int b = rem >> 6;
    const int c = rem & 63;
    const float* xr = x + ((size_t)b * SS + (size_t)t * CHK + c) * DD;
    float s0 = 0.0f, s1 = 0.0f, s2 = 0.0f;
#pragma unroll
    for (int jj = 0; jj < DD / 64; ++jj) {
        const int j = lane + jj * 64;
        const float xv = xr[j];
        s0 = fmaf(xv, gdw[j], s0);
        s1 = fmaf(xv, glw[j], s1);
        s2 = fmaf(xv, gmw[j], s2);
    }
#pragma unroll
    for (int m = 32; m >= 1; m >>= 1) {
        s0 += __shfl_xor(s0, m);
        s1 += __shfl_xor(s1, m);
        s2 += __shfl_xor(s2, m);
    }
    if (lane == 0) {
        gtok[0 * (NCHK * TOK) + wid] = sigmoidf_(s0 + gdb[0]);
        gtok[1 * (NCHK * TOK) + wid] = sigmoidf_(s1 + glb[0]);
        gtok[2 * (NCHK * TOK) + wid] = sigmoidf_(s2 + gmb[0]);
    }
}

__global__ __launch_bounds__(256) void gates_red_k(
    const float* __restrict__ gtok, float* __restrict__ gates)
{
    __shared__ float sm[256];
    const int t = blockIdx.x;
    for (int g = 0; g < 3; ++g) {
        sm[threadIdx.x] = gtok[g * (NCHK * TOK) + t * TOK + threadIdx.x];
        __syncthreads();
        for (int s = 128; s >= 1; s >>= 1) {
            if (threadIdx.x < s) sm[threadIdx.x] += sm[threadIdx.x + s];
            __syncthreads();
        }
        if (threadIdx.x == 0) gates[g * NCHK + t] = sm[0] * (1.0f / 256.0f);
        __syncthreads();
    }
}

__global__ __launch_bounds__(256) void out_k(const ushort* __restrict__ ycall,
                                             const ushort* __restrict__ Woutb,
                                             float* __restrict__ out) {
    __shared__ ushort As[64 * SA], Bs[64 * SA];
    f32x4 acc[2][2]; zacc(acc);
    const int m0 = blockIdx.y * 64, n0 = blockIdx.x * 64;
    gemm_core(ycall, DD, false, Woutb, DD, false, DD, m0, n0, As, Bs, acc);
    epilogue(m0, n0, acc, [&](int row, int col, float val) {
        const int t = row >> 8, b = (row >> 6) & 3, c = row & 63;
        out[((size_t)b * SS + (size_t)t * CHK + c) * DD + col] = val;
    });
}

// ---------------------------------------------------------------------------
extern "C" void kernel_launch(void* const* d_in, const int* in_sizes, int n_in,
                              void* d_out, int out_size, void* d_ws, size_t ws_size,
                              hipStream_t stream)
{
    const float* x    = (const float*)d_in[0];
    const float* Wk   = (const float*)d_in[1];
    const float* Wv   = (const float*)d_in[2];
    const float* Wq   = (const float*)d_in[3];
    const float* Wout = (const float*)d_in[4];
    const float* Wm1  = (const float*)d_in[5];
    const float* Wm2  = (const float*)d_in[6];
    const float* gdw  = (const float*)d_in[7];
    const float* gdb  = (const float*)d_in[8];
    const float* glw  = (const float*)d_in[9];
    const float* glb  = (const float*)d_in[10];
    const float* gmw  = (const float*)d_in[11];
    const float* gmb  = (const float*)d_in[12];
    float* out = (float*)d_out;

    char* w = (char*)d_ws;
    size_t off = 0;
    auto alloc = [&](size_t bytes) {
        off = (off + 255) & ~(size_t)255;
        char* p = w + off;
        off += bytes;
        return p;
    };

    const size_t M = (size_t)BB * SS;                 // 16384
    float*  kpre = (float*)alloc(M * DD * 4);         // f32 chunk-major; ycall aliases
    char*   qreg = alloc(M * DD * 4);                 // qpre f32; scan temps alias after l2n
    float*  qpre = (float*)qreg;
    ushort* xb   = (ushort*)alloc(M * DD * 2);        // ktb aliases after projections
    ushort* qtb  = (ushort*)alloc(M * DD * 2);
    ushort* vcb  = (ushort*)alloc(M * DD * 2);
    float*  d1   = (float*)alloc((size_t)HH * DD * 4);  // state: 4 contiguous blocks
    float*  d2   = (float*)alloc((size_t)HH * DD * 4);
    float*  m1   = (float*)alloc((size_t)HH * DD * 4);
    float*  m2   = (float*)alloc((size_t)HH * DD * 4);
    ushort* Wkb  = (ushort*)alloc((size_t)DD * DD * 2);
    ushort* Wvb  = (ushort*)alloc((size_t)DD * DD * 2);
    ushort* Wqb  = (ushort*)alloc((size_t)DD * DD * 2);
    ushort* Woutb= (ushort*)alloc((size_t)DD * DD * 2);
    float*  gtok = (float*)alloc((size_t)3 * NCHK * TOK * 4);
    float*  gates= (float*)alloc((size_t)3 * NCHK * 4);
    unsigned* bar = (unsigned*)alloc(256);            // grid barrier: cnt, gen

    ushort* ktb   = xb;             // alias: xb dead after projection GEMMs
    ushort* ycall = (ushort*)kpre;  // alias: kpre dead after l2norm

    // scan temporaries carved from qpre region (dead after l2n):
    size_t qo = 0;
    auto qalloc = [&](size_t bytes) { char* p = qreg + qo; qo += bytes; return p; };
    ushort* a1b0  = (ushort*)qalloc((size_t)TOK * HH * 2);
    ushort* a1b1  = (ushort*)qalloc((size_t)TOK * HH * 2);
    float*  ds10  = (float*)qalloc((size_t)TOK * HH * 4);
    float*  ds11  = (float*)qalloc((size_t)TOK * HH * 4);
    ushort* db1b  = (ushort*)qalloc((size_t)TOK * HH * 2);
    ushort* db2b0 = (ushort*)qalloc((size_t)TOK * DD * 2);
    ushort* db2b1 = (ushort*)qalloc((size_t)TOK * DD * 2);
    ushort* hbb   = (ushort*)qalloc((size_t)TOK * HH * 2);
    ushort* W1eb0 = (ushort*)qalloc((size_t)HH * DD * 2);
    ushort* W1eb1 = (ushort*)qalloc((size_t)HH * DD * 2);
    ushort* W2eb0 = (ushort*)qalloc((size_t)HH * DD * 2);
    ushort* W2eb1 = (ushort*)qalloc((size_t)HH * DD * 2);

    // zero scan state (d1,d2,m1,m2 contiguous) and the grid barrier
    hipMemsetAsync(d1, 0, (size_t)4 * HH * DD * 4, stream);
    hipMemsetAsync(bar, 0, 256, stream);

    const dim3 blk(256);

    // bf16 conversions of x and projection weights
    conv_k<<<dim3((M * DD / 4 + 255) / 256), blk, 0, stream>>>(x, xb, (int)(M * DD / 4));
    conv_k<<<dim3((DD * DD / 4 + 255) / 256), blk, 0, stream>>>(Wk, Wkb, DD * DD / 4);
    conv_k<<<dim3((DD * DD / 4 + 255) / 256), blk, 0, stream>>>(Wv, Wvb, DD * DD / 4);
    conv_k<<<dim3((DD * DD / 4 + 255) / 256), blk, 0, stream>>>(Wq, Wqb, DD * DD / 4);
    conv_k<<<dim3((DD * DD / 4 + 255) / 256), blk, 0, stream>>>(Wout, Woutb, DD * DD / 4);

    // projections (chunk-major epilogue)
    proj_k<0><<<dim3(DD / 64, M / 64), blk, 0, stream>>>(xb, Wkb, kpre, nullptr);
    proj_k<1><<<dim3(DD / 64, M / 64), blk, 0, stream>>>(xb, Wvb, nullptr, vcb);
    proj_k<0><<<dim3(DD / 64, M / 64), blk, 0, stream>>>(xb, Wqb, qpre, nullptr);

    // l2norm + bf16 (ktb aliases xb; qpre consumed here)
    l2n_k<<<dim3(M / 4, 2), blk, 0, stream>>>(kpre, qpre, ktb, qtb);

    // initial effective weights (into qpre region — now dead)
    conv_k<<<dim3((HH * DD / 4 + 255) / 256), blk, 0, stream>>>(Wm1, W1eb0, HH * DD / 4);
    conv_k<<<dim3((HH * DD / 4 + 255) / 256), blk, 0, stream>>>(Wm2, W2eb0, HH * DD / 4);

    // gates
    gates_tok_k<<<dim3(M / 4), blk, 0, stream>>>(x, gdw, gdb, glw, glb, gmw, gmb, gtok);
    gates_red_k<<<dim3(NCHK), blk, 0, stream>>>(gtok, gates);

    // persistent scan (all 64 chunks) — plain launch, custom device barrier
    ScanArgs sa;
    sa.ktb = ktb; sa.vcb = vcb; sa.qtb = qtb;
    sa.a1b0 = a1b0; sa.a1b1 = a1b1;
    sa.ds10 = ds10; sa.ds11 = ds11;
    sa.db1b = db1b; sa.db2b0 = db2b0; sa.db2b1 = db2b1; sa.hbb = hbb;
    sa.W1eb0 = W1eb0; sa.W1eb1 = W1eb1; sa.W2eb0 = W2eb0; sa.W2eb1 = W2eb1;
    sa.m1 = m1; sa.d1 = d1; sa.m2 = m2; sa.d2 = d2;
    sa.Wm1 = Wm1; sa.Wm2 = Wm2; sa.gates = gates;
    sa.ycall = ycall;
    sa.bcnt = bar; sa.bgen = bar + 64;   // separate cachelines
    scan_k<<<dim3(GRID_BLKS), blk, 0, stream>>>(sa);

    // final projection + scatter to [B,S,D]
    out_k<<<dim3(DD / 64, M / 64), blk, 0, stream>>>(ycall, Woutb, out);
}

// Round 5
// 7881.548 us; speedup vs baseline: 1.0271x; 1.0271x over previous
//
#include <hip/hip_runtime.h>
#include <cmath>

#define DD   512
#define HH   1024
#define BB   4
#define SS   4096
#define CHK  64
#define NCHK 64
#define TOK  256
#define SA   72   /* padded LDS row stride in bf16 elements */
#define GRID_BLKS 256
#define FLAG_STRIDE 16   /* u32s per flag slot = 64B */

static constexpr float ERRSCALE = 2.0f / (float)(TOK * DD);

typedef __attribute__((ext_vector_type(8))) short bf16x8;
typedef __attribute__((ext_vector_type(4))) float f32x4;

__device__ __forceinline__ float sigmoidf_(float v) { return 1.0f / (1.0f + expf(-v)); }
__device__ __forceinline__ float clip1f_(float v) { return fminf(fmaxf(v, -1.0f), 1.0f); }

__device__ __forceinline__ ushort f2b(float f) {
    union { float f; unsigned u; } v; v.f = f;
    return (ushort)((v.u + 0x7fffu + ((v.u >> 16) & 1u)) >> 16);
}
__device__ __forceinline__ float b2f(ushort u) {
    union { unsigned u; float f; } v; v.u = ((unsigned)u) << 16;
    return v.f;
}

// ---------------------------------------------------------------------------
// Flag-array grid barrier (no shared-line RMW chain).
// Each block release-stores `target` to its own padded flag; block 0's threads
// poll all flags in parallel, then publish `target` to gen; others spin on gen.
// flags/gen zeroed host-side before launch; target increments monotonically.
// ---------------------------------------------------------------------------
__device__ __forceinline__ void gbar(unsigned* flags, unsigned* gen, unsigned target) {
    __syncthreads();
    if (blockIdx.x == 0) {
        if (threadIdx.x != 0) {
            unsigned* f = flags + (size_t)threadIdx.x * FLAG_STRIDE;
            while (__hip_atomic_load(f, __ATOMIC_ACQUIRE, __HIP_MEMORY_SCOPE_AGENT) < target)
                __builtin_amdgcn_s_sleep(1);
        }
        __syncthreads();
        if (threadIdx.x == 0) {
            __threadfence();
            __hip_atomic_store(gen, target, __ATOMIC_RELEASE, __HIP_MEMORY_SCOPE_AGENT);
        }
    } else {
        if (threadIdx.x == 0) {
            __threadfence();   // release: publish this block's prior writes
            __hip_atomic_store(flags + (size_t)blockIdx.x * FLAG_STRIDE, target,
                               __ATOMIC_RELEASE, __HIP_MEMORY_SCOPE_AGENT);
            while (__hip_atomic_load(gen, __ATOMIC_RELAXED, __HIP_MEMORY_SCOPE_AGENT) < target)
                __builtin_amdgcn_s_sleep(1);
            __threadfence();   // acquire: see all other blocks' writes
        }
    }
    __syncthreads();
}

// ---------------------------------------------------------------------------
// LDS staging (canonical layout S[row][k], row stride SA)
// ---------------------------------------------------------------------------
__device__ __forceinline__ void stage_n(const ushort* __restrict__ G, int ld,
                                        int r0, int k0, ushort* S, int tid) {
#pragma unroll
    for (int p = 0; p < 2; ++p) {
        const int c = tid + p * 256;
        const int r = c >> 3, o = c & 7;
        *(float4*)(S + r * SA + o * 8) =
            *(const float4*)(G + (size_t)(r0 + r) * ld + k0 + o * 8);
    }
}
__device__ __forceinline__ void stage_t(const ushort* __restrict__ G, int ld,
                                        int c0, int k0, ushort* S, int tid) {
    const int kr = tid & 63;
    const int mo0 = (tid >> 6) * 2;
#pragma unroll
    for (int p = 0; p < 2; ++p) {
        const int mo = (mo0 + p) * 8;
        const float4 v = *(const float4*)(G + (size_t)(k0 + kr) * ld + c0 + mo);
        ushort u[8];
        __builtin_memcpy(u, &v, 16);
#pragma unroll
        for (int j = 0; j < 8; ++j) S[(mo + j) * SA + kr] = u[j];
    }
}

// 64x64 block tile MFMA core, 4 waves of 32x32, K steps of 64.
__device__ __forceinline__ void gemm_core(
    const ushort* __restrict__ A, int lda, bool ta,
    const ushort* __restrict__ B, int ldb, bool tb,
    int K, int m0, int n0, ushort* As, ushort* Bs, f32x4 acc[2][2])
{
    const int tid = threadIdx.x;
    const int lane = tid & 63;
    const int w = tid >> 6;
    const int wr = (w >> 1) * 32, wc = (w & 1) * 32;
    const int lr = lane & 15, lg = lane >> 4;

    for (int k0 = 0; k0 < K; k0 += 64) {
        if (ta) stage_t(A, lda, m0, k0, As, tid); else stage_n(A, lda, m0, k0, As, tid);
        if (tb) stage_t(B, ldb, n0, k0, Bs, tid); else stage_n(B, ldb, n0, k0, Bs, tid);
        __syncthreads();
#pragma unroll
        for (int ks = 0; ks < 2; ++ks) {
            bf16x8 af[2], bfr[2];
#pragma unroll
            for (int mi = 0; mi < 2; ++mi)
                af[mi] = *(const bf16x8*)(As + (wr + mi * 16 + lr) * SA + ks * 32 + lg * 8);
#pragma unroll
            for (int ni = 0; ni < 2; ++ni)
                bfr[ni] = *(const bf16x8*)(Bs + (wc + ni * 16 + lr) * SA + ks * 32 + lg * 8);
#pragma unroll
            for (int mi = 0; mi < 2; ++mi)
#pragma unroll
                for (int ni = 0; ni < 2; ++ni)
                    acc[mi][ni] = __builtin_amdgcn_mfma_f32_16x16x32_bf16(
                        af[mi], bfr[ni], acc[mi][ni], 0, 0, 0);
        }
        __syncthreads();
    }
}

template<typename F>
__device__ __forceinline__ void epilogue(int m0, int n0, const f32x4 acc[2][2], F&& f) {
    const int lane = threadIdx.x & 63, w = threadIdx.x >> 6;
    const int wr = (w >> 1) * 32, wc = (w & 1) * 32;
    const int lr = lane & 15, lg = lane >> 4;
#pragma unroll
    for (int mi = 0; mi < 2; ++mi)
#pragma unroll
        for (int ni = 0; ni < 2; ++ni)
#pragma unroll
            for (int r = 0; r < 4; ++r)
                f(m0 + wr + mi * 16 + lg * 4 + r, n0 + wc + ni * 16 + lr, acc[mi][ni][r]);
}

__device__ __forceinline__ void zacc(f32x4 acc[2][2]) {
#pragma unroll
    for (int i = 0; i < 2; ++i)
#pragma unroll
        for (int j = 0; j < 2; ++j) acc[i][j] = 0.0f;
}

// ---------------------------------------------------------------------------
// Scan phase ops
// ---------------------------------------------------------------------------
__device__ __forceinline__ void op_s1(const ushort* kt, const ushort* W1e,
                                      ushort* a1, float* ds, int tile,
                                      ushort* As, ushort* Bs) {
    f32x4 acc[2][2]; zacc(acc);
    const int m0 = (tile >> 4) * 64, n0 = (tile & 15) * 64;
    gemm_core(kt, DD, false, W1e, DD, false, DD, m0, n0, As, Bs, acc);
    epilogue(m0, n0, acc, [&](int r, int c, float v) {
        const size_t i = (size_t)r * HH + c;
        const float sg = sigmoidf_(v);
        a1[i] = f2b(v * sg);
        ds[i] = sg * (1.0f + v * (1.0f - sg));
    });
}

__device__ __forceinline__ void op_s2(const ushort* a1, const ushort* W2e,
                                      const ushort* vt, ushort* db2, int tile,
                                      ushort* As, ushort* Bs) {
    f32x4 acc[2][2]; zacc(acc);
    const int m0 = (tile >> 3) * 64, n0 = (tile & 7) * 64;
    gemm_core(a1, HH, false, W2e, HH, false, HH, m0, n0, As, Bs, acc);
    epilogue(m0, n0, acc, [&](int r, int c, float v) {
        const size_t i = (size_t)r * DD + c;
        const float e = clip1f_(v - b2f(vt[i]));
        db2[i] = f2b(e * ERRSCALE);
    });
}

__device__ __forceinline__ void op_s3(const ushort* db2, const ushort* W2e,
                                      const float* ds, ushort* db1, int tile,
                                      ushort* As, ushort* Bs) {
    f32x4 acc[2][2]; zacc(acc);
    const int m0 = (tile >> 4) * 64, n0 = (tile & 15) * 64;
    gemm_core(db2, DD, false, W2e, HH, true, DD, m0, n0, As, Bs, acc);
    epilogue(m0, n0, acc, [&](int r, int c, float v) {
        const size_t i = (size_t)r * HH + c;
        db1[i] = f2b(v * ds[i]);
    });
}

__device__ __forceinline__ void op_g1upd(const ushort* db1, const ushort* kt,
    float* m1, float* d1, const float* Wm1, ushort* W1n,
    float dec, float lrg, float eta, int tile, ushort* As, ushort* Bs) {
    f32x4 acc[2][2]; zacc(acc);
    const int i0 = (tile >> 3) * 64, j0 = (tile & 7) * 64;
    gemm_core(db1, HH, true, kt, DD, true, TOK, i0, j0, As, Bs, acc);
    epilogue(i0, j0, acc, [&](int r, int c, float v) {
        const size_t i = (size_t)r * DD + c;
        const float g = clip1f_(v);
        const float mn = eta * m1[i] - lrg * g;
        m1[i] = mn;
        const float dn = (1.0f - dec) * d1[i] + mn;
        d1[i] = dn;
        W1n[i] = f2b(Wm1[i] + dn);
    });
}

__device__ __forceinline__ void op_g2upd(const ushort* db2, const ushort* a1,
    float* m2, float* d2, const float* Wm2, ushort* W2n,
    float dec, float lrg, float eta, int tile, ushort* As, ushort* Bs) {
    f32x4 acc[2][2]; zacc(acc);
    const int i0 = (tile >> 4) * 64, j0 = (tile & 15) * 64;
    gemm_core(db2, DD, true, a1, HH, true, TOK, i0, j0, As, Bs, acc);
    epilogue(i0, j0, acc, [&](int r, int c, float v) {
        const size_t i = (size_t)r * HH + c;
        const float g = clip1f_(v);
        const float mn = eta * m2[i] - lrg * g;
        m2[i] = mn;
        const float dn = (1.0f - dec) * d2[i] + mn;
        d2[i] = dn;
        W2n[i] = f2b(Wm2[i] + dn);
    });
}

__device__ __forceinline__ void op_s6(const ushort* qt, const ushort* W1e,
                                      ushort* h, int tile, ushort* As, ushort* Bs) {
    f32x4 acc[2][2]; zacc(acc);
    const int m0 = (tile >> 4) * 64, n0 = (tile & 15) * 64;
    gemm_core(qt, DD, false, W1e, DD, false, DD, m0, n0, As, Bs, acc);
    epilogue(m0, n0, acc, [&](int r, int c, float v) {
        const float sg = sigmoidf_(v);
        h[(size_t)r * HH + c] = f2b(v * sg);
    });
}

__device__ __forceinline__ void op_s7(const ushort* h, const ushort* W2e,
                                      ushort* y, int tile, ushort* As, ushort* Bs) {
    f32x4 acc[2][2]; zacc(acc);
    const int m0 = (tile >> 3) * 64, n0 = (tile & 7) * 64;
    gemm_core(h, HH, false, W2e, HH, false, HH, m0, n0, As, Bs, acc);
    epilogue(m0, n0, acc, [&](int r, int c, float v) {
        y[(size_t)r * DD + c] = f2b(v);
    });
}

// ---------------------------------------------------------------------------
// Persistent scan kernel: all 64 chunks, 4 grid barriers per chunk.
// P1 = S3(t) || g2upd(t); P2 = g1upd(t); P3 = S6(t) || S1(t+1);
// P4 = S7(t) || S2(t+1).  Weights/activations parity double-buffered.
// ---------------------------------------------------------------------------
struct ScanArgs {
    const ushort *ktb, *vcb, *qtb;
    ushort *a1b0, *a1b1;
    float  *ds10, *ds11;
    ushort *db1b, *db2b0, *db2b1, *hbb;
    ushort *W1eb0, *W1eb1, *W2eb0, *W2eb1;
    float  *m1, *d1, *m2, *d2;
    const float *Wm1, *Wm2, *gates;
    ushort *ycall;
    unsigned *flags, *gen;
};

__global__ __launch_bounds__(256) void scan_k(ScanArgs p) {
    __shared__ ushort As[64 * SA];
    __shared__ ushort Bs[64 * SA];
    const int bid = blockIdx.x;
    unsigned bt = 0;

    // prologue: chunk-0 forward
    if (bid < 64) op_s1(p.ktb, p.W1eb0, p.a1b0, p.ds10, bid, As, Bs);
    gbar(p.flags, p.gen, ++bt);
    if (bid < 32) op_s2(p.a1b0, p.W2eb0, p.vcb, p.db2b0, bid, As, Bs);
    gbar(p.flags, p.gen, ++bt);

    for (int t = 0; t < NCHK; ++t) {
        const int par = t & 1;
        const ushort* kt = p.ktb + (size_t)t * TOK * DD;
        const ushort* qt = p.qtb + (size_t)t * TOK * DD;
        ushort* a1c  = par ? p.a1b1 : p.a1b0;
        ushort* a1n  = par ? p.a1b0 : p.a1b1;
        float*  ds1c = par ? p.ds11 : p.ds10;
        float*  ds1n = par ? p.ds10 : p.ds11;
        ushort* db2c = par ? p.db2b1 : p.db2b0;
        ushort* db2n = par ? p.db2b0 : p.db2b1;
        ushort* W1n  = par ? p.W1eb0 : p.W1eb1;
        const ushort* W2o = par ? p.W2eb1 : p.W2eb0;
        ushort* W2n  = par ? p.W2eb0 : p.W2eb1;
        const float dec = p.gates[t];
        const float lrg = p.gates[NCHK + t];
        const float eta = p.gates[2 * NCHK + t];

        // P1: db1 = (db2 @ W2e_old) * silu'(pre1)  ||  g2 + m2/d2/W2e update
        if (bid < 64)
            op_s3(db2c, W2o, ds1c, p.db1b, bid, As, Bs);
        else if (bid < 192)
            op_g2upd(db2c, a1c, p.m2, p.d2, p.Wm2, W2n, dec, lrg, eta, bid - 64, As, Bs);
        gbar(p.flags, p.gen, ++bt);

        // P2: g1 + m1/d1/W1e update
        if (bid < 128)
            op_g1upd(p.db1b, kt, p.m1, p.d1, p.Wm1, W1n, dec, lrg, eta, bid, As, Bs);
        gbar(p.flags, p.gen, ++bt);

        // P3: h(t) = silu(q @ W1e_new^T)  ||  S1(t+1) with W1e_new
        if (bid < 64)
            op_s6(qt, W1n, p.hbb, bid, As, Bs);
        else if (bid < 128 && t + 1 < NCHK)
            op_s1(p.ktb + (size_t)(t + 1) * TOK * DD, W1n, a1n, ds1n, bid - 64, As, Bs);
        gbar(p.flags, p.gen, ++bt);

        // P4: y(t) = h @ W2e_new^T  ||  S2(t+1) with W2e_new
        if (bid < 32)
            op_s7(p.hbb, W2n, p.ycall + (size_t)t * TOK * DD, bid, As, Bs);
        else if (bid < 64 && t + 1 < NCHK)
            op_s2(a1n, W2n, p.vcb + (size_t)(t + 1) * TOK * DD, db2n, bid - 32, As, Bs);
        gbar(p.flags, p.gen, ++bt);
    }
}

// ---------------------------------------------------------------------------
// Pre/post kernels
// ---------------------------------------------------------------------------
__global__ __launch_bounds__(256) void conv_k(const float* __restrict__ s,
                                              ushort* __restrict__ d, int n4) {
    const int i = blockIdx.x * 256 + threadIdx.x;
    if (i < n4) {
        const float4 v = ((const float4*)s)[i];
        ushort4 o;
        o.x = f2b(v.x); o.y = f2b(v.y); o.z = f2b(v.z); o.w = f2b(v.w);
        ((ushort4*)d)[i] = o;
    }
}

template<int OM>
__global__ __launch_bounds__(256) void proj_k(const ushort* __restrict__ xb,
                                              const ushort* __restrict__ Wb,
                                              float* __restrict__ df,
                                              ushort* __restrict__ db) {
    __shared__ ushort As[64 * SA], Bs[64 * SA];
    f32x4 acc[2][2]; zacc(acc);
    const int m0 = blockIdx.y * 64, n0 = blockIdx.x * 64;
    gemm_core(xb, DD, false, Wb, DD, false, DD, m0, n0, As, Bs, acc);
    epilogue(m0, n0, acc, [&](int row, int col, float val) {
        const int b = row >> 12, s = row & (SS - 1);
        const int t = s >> 6, c = s & 63;
        const size_t orow = (size_t)((t << 8) | (b << 6) | c);
        if (OM == 0) df[orow * DD + col] = val;
        else         db[orow * DD + col] = f2b(val);
    });
}

__global__ __launch_bounds__(256) void l2n_k(const float* __restrict__ kp,
                                             const float* __restrict__ qp,
                                             ushort* __restrict__ kb,
                                             ushort* __restrict__ qb) {
    const float* src = blockIdx.y ? qp : kp;
    ushort* dst = blockIdx.y ? qb : kb;
    const int row = blockIdx.x * 4 + (threadIdx.x >> 6);
    const int lane = threadIdx.x & 63;
    const float4* p = (const float4*)(src + (size_t)row * DD);
    float4 v0 = p[lane], v1 = p[lane + 64];
    float ss = v0.x * v0.x + v0.y * v0.y + v0.z * v0.z + v0.w * v0.w
             + v1.x * v1.x + v1.y * v1.y + v1.z * v1.z + v1.w * v1.w;
#pragma unroll
    for (int m = 32; m >= 1; m >>= 1) ss += __shfl_xor(ss, m);
    const float sc = 1.0f / (sqrtf(ss) + 1e-8f);
    ushort4 o0, o1;
    o0.x = f2b(v0.x * sc); o0.y = f2b(v0.y * sc); o0.z = f2b(v0.z * sc); o0.w = f2b(v0.w * sc);
    o1.x = f2b(v1.x * sc); o1.y = f2b(v1.y * sc); o1.z = f2b(v1.z * sc); o1.w = f2b(v1.w * sc);
    *(ushort4*)(dst + (size_t)row * DD + lane * 4) = o0;
    *(ushort4*)(dst + (size_t)row * DD + 256 + lane * 4) = o1;
}

__global__ __launch_bounds__(256) void gates_tok_k(
    const float* __restrict__ x,
    const float* __restrict__ gdw, const float* __restrict__ gdb,
    const float* __restrict__ glw, const float* __restrict__ glb,
    const float* __restrict__ gmw, const float* __restrict__ gmb,
    float* __restrict__ gtok)
{
    const int wid = (blockIdx.x * 256 + threadIdx.x) >> 6;
    const int lane = threadIdx.x & 63;
    const int t = wid >> 8;
    const int rem = wid & 255;
    const int b = rem >> 6;
    const int c = rem & 63;
    const float* xr = x + ((size_t)b * SS + (size_t)t * CHK + c) * DD;
    float s0 = 0.0f, s1 = 0.0f, s2 = 0.0f;
#pragma unroll
    for (int jj = 0; jj < DD / 64; ++jj) {
        const int j = lane + jj * 64;
        const float xv = xr[j];
        s0 = fmaf(xv, gdw[j], s0);
        s1 = fmaf(xv, glw[j], s1);
        s2 = fmaf(xv, gmw[j], s2);
    }
#pragma unroll
    for (int m = 32; m >= 1; m >>= 1) {
        s0 += __shfl_xor(s0, m);
        s1 += __shfl_xor(s1, m);
        s2 += __shfl_xor(s2, m);
    }
    if (lane == 0) {
        gtok[0 * (NCHK * TOK) + wid] = sigmoidf_(s0 + gdb[0]);
        gtok[1 * (NCHK * TOK) + wid] = sigmoidf_(s1 + glb[0]);
        gtok[2 * (NCHK * TOK) + wid] = sigmoidf_(s2 + gmb[0]);
    }
}

__global__ __launch_bounds__(256) void gates_red_k(
    const float* __restrict__ gtok, float* __restrict__ gates)
{
    __shared__ float sm[256];
    const int t = blockIdx.x;
    for (int g = 0; g < 3; ++g) {
        sm[threadIdx.x] = gtok[g * (NCHK * TOK) + t * TOK + threadIdx.x];
        __syncthreads();
        for (int s = 128; s >= 1; s >>= 1) {
            if (threadIdx.x < s) sm[threadIdx.x] += sm[threadIdx.x + s];
            __syncthreads();
        }
        if (threadIdx.x == 0) gates[g * NCHK + t] = sm[0] * (1.0f / 256.0f);
        __syncthreads();
    }
}

__global__ __launch_bounds__(256) void out_k(const ushort* __restrict__ ycall,
                                             const ushort* __restrict__ Woutb,
                                             float* __restrict__ out) {
    __shared__ ushort As[64 * SA], Bs[64 * SA];
    f32x4 acc[2][2]; zacc(acc);
    const int m0 = blockIdx.y * 64, n0 = blockIdx.x * 64;
    gemm_core(ycall, DD, false, Woutb, DD, false, DD, m0, n0, As, Bs, acc);
    epilogue(m0, n0, acc, [&](int row, int col, float val) {
        const int t = row >> 8, b = (row >> 6) & 3, c = row & 63;
        out[((size_t)b * SS + (size_t)t * CHK + c) * DD + col] = val;
    });
}

// ---------------------------------------------------------------------------
extern "C" void kernel_launch(void* const* d_in, const int* in_sizes, int n_in,
                              void* d_out, int out_size, void* d_ws, size_t ws_size,
                              hipStream_t stream)
{
    const float* x    = (const float*)d_in[0];
    const float* Wk   = (const float*)d_in[1];
    const float* Wv   = (const float*)d_in[2];
    const float* Wq   = (const float*)d_in[3];
    const float* Wout = (const float*)d_in[4];
    const float* Wm1  = (const float*)d_in[5];
    const float* Wm2  = (const float*)d_in[6];
    const float* gdw  = (const float*)d_in[7];
    const float* gdb  = (const float*)d_in[8];
    const float* glw  = (const float*)d_in[9];
    const float* glb  = (const float*)d_in[10];
    const float* gmw  = (const float*)d_in[11];
    const float* gmb  = (const float*)d_in[12];
    float* out = (float*)d_out;

    char* w = (char*)d_ws;
    size_t off = 0;
    auto alloc = [&](size_t bytes) {
        off = (off + 255) & ~(size_t)255;
        char* p = w + off;
        off += bytes;
        return p;
    };

    const size_t M = (size_t)BB * SS;                 // 16384
    float*  kpre = (float*)alloc(M * DD * 4);         // f32 chunk-major; ycall aliases
    char*   qreg = alloc(M * DD * 4);                 // qpre f32; scan temps alias after l2n
    float*  qpre = (float*)qreg;
    ushort* xb   = (ushort*)alloc(M * DD * 2);        // ktb aliases after projections
    ushort* qtb  = (ushort*)alloc(M * DD * 2);
    ushort* vcb  = (ushort*)alloc(M * DD * 2);
    float*  d1   = (float*)alloc((size_t)HH * DD * 4);  // state: 4 contiguous blocks
    float*  d2   = (float*)alloc((size_t)HH * DD * 4);
    float*  m1   = (float*)alloc((size_t)HH * DD * 4);
    float*  m2   = (float*)alloc((size_t)HH * DD * 4);
    ushort* Wkb  = (ushort*)alloc((size_t)DD * DD * 2);
    ushort* Wvb  = (ushort*)alloc((size_t)DD * DD * 2);
    ushort* Wqb  = (ushort*)alloc((size_t)DD * DD * 2);
    ushort* Woutb= (ushort*)alloc((size_t)DD * DD * 2);
    float*  gtok = (float*)alloc((size_t)3 * NCHK * TOK * 4);
    float*  gates= (float*)alloc((size_t)3 * NCHK * 4);
    unsigned* bar = (unsigned*)alloc((size_t)(GRID_BLKS * FLAG_STRIDE + 64) * 4);

    ushort* ktb   = xb;             // alias: xb dead after projection GEMMs
    ushort* ycall = (ushort*)kpre;  // alias: kpre dead after l2norm

    // scan temporaries carved from qpre region (dead after l2n):
    size_t qo = 0;
    auto qalloc = [&](size_t bytes) { char* p = qreg + qo; qo += bytes; return p; };
    ushort* a1b0  = (ushort*)qalloc((size_t)TOK * HH * 2);
    ushort* a1b1  = (ushort*)qalloc((size_t)TOK * HH * 2);
    float*  ds10  = (float*)qalloc((size_t)TOK * HH * 4);
    float*  ds11  = (float*)qalloc((size_t)TOK * HH * 4);
    ushort* db1b  = (ushort*)qalloc((size_t)TOK * HH * 2);
    ushort* db2b0 = (ushort*)qalloc((size_t)TOK * DD * 2);
    ushort* db2b1 = (ushort*)qalloc((size_t)TOK * DD * 2);
    ushort* hbb   = (ushort*)qalloc((size_t)TOK * HH * 2);
    ushort* W1eb0 = (ushort*)qalloc((size_t)HH * DD * 2);
    ushort* W1eb1 = (ushort*)qalloc((size_t)HH * DD * 2);
    ushort* W2eb0 = (ushort*)qalloc((size_t)HH * DD * 2);
    ushort* W2eb1 = (ushort*)qalloc((size_t)HH * DD * 2);

    // zero scan state (d1,d2,m1,m2 contiguous) and the barrier flags/gen
    hipMemsetAsync(d1, 0, (size_t)4 * HH * DD * 4, stream);
    hipMemsetAsync(bar, 0, (size_t)(GRID_BLKS * FLAG_STRIDE + 64) * 4, stream);

    const dim3 blk(256);

    // bf16 conversions of x and projection weights
    conv_k<<<dim3((M * DD / 4 + 255) / 256), blk, 0, stream>>>(x, xb, (int)(M * DD / 4));
    conv_k<<<dim3((DD * DD / 4 + 255) / 256), blk, 0, stream>>>(Wk, Wkb, DD * DD / 4);
    conv_k<<<dim3((DD * DD / 4 + 255) / 256), blk, 0, stream>>>(Wv, Wvb, DD * DD / 4);
    conv_k<<<dim3((DD * DD / 4 + 255) / 256), blk, 0, stream>>>(Wq, Wqb, DD * DD / 4);
    conv_k<<<dim3((DD * DD / 4 + 255) / 256), blk, 0, stream>>>(Wout, Woutb, DD * DD / 4);

    // projections (chunk-major epilogue)
    proj_k<0><<<dim3(DD / 64, M / 64), blk, 0, stream>>>(xb, Wkb, kpre, nullptr);
    proj_k<1><<<dim3(DD / 64, M / 64), blk, 0, stream>>>(xb, Wvb, nullptr, vcb);
    proj_k<0><<<dim3(DD / 64, M / 64), blk, 0, stream>>>(xb, Wqb, qpre, nullptr);

    // l2norm + bf16 (ktb aliases xb; qpre consumed here)
    l2n_k<<<dim3(M / 4, 2), blk, 0, stream>>>(kpre, qpre, ktb, qtb);

    // initial effective weights (into qpre region — now dead)
    conv_k<<<dim3((HH * DD / 4 + 255) / 256), blk, 0, stream>>>(Wm1, W1eb0, HH * DD / 4);
    conv_k<<<dim3((HH * DD / 4 + 255) / 256), blk, 0, stream>>>(Wm2, W2eb0, HH * DD / 4);

    // gates
    gates_tok_k<<<dim3(M / 4), blk, 0, stream>>>(x, gdw, gdb, glw, glb, gmw, gmb, gtok);
    gates_red_k<<<dim3(NCHK), blk, 0, stream>>>(gtok, gates);

    // persistent scan (all 64 chunks) — plain launch, flag-array grid barrier
    ScanArgs sa;
    sa.ktb = ktb; sa.vcb = vcb; sa.qtb = qtb;
    sa.a1b0 = a1b0; sa.a1b1 = a1b1;
    sa.ds10 = ds10; sa.ds11 = ds11;
    sa.db1b = db1b; sa.db2b0 = db2b0; sa.db2b1 = db2b1; sa.hbb = hbb;
    sa.W1eb0 = W1eb0; sa.W1eb1 = W1eb1; sa.W2eb0 = W2eb0; sa.W2eb1 = W2eb1;
    sa.m1 = m1; sa.d1 = d1; sa.m2 = m2; sa.d2 = d2;
    sa.Wm1 = Wm1; sa.Wm2 = Wm2; sa.gates = gates;
    sa.ycall = ycall;
    sa.flags = bar; sa.gen = bar + GRID_BLKS * FLAG_STRIDE;
    scan_k<<<dim3(GRID_BLKS), blk, 0, stream>>>(sa);

    // final projection + scatter to [B,S,D]
    out_k<<<dim3(DD / 64, M / 64), blk, 0, stream>>>(ycall, Woutb, out);
}